// Round 3
// baseline (3670.260 us; speedup 1.0000x reference)
//
#include <hip/hip_runtime.h>
#include <math.h>

// Problem constants
#define B 4
#define C 64
#define IMG_H 256
#define IMG_W 256
#define NN 65536   // IMG_H*IMG_W
#define HEADS 8
#define CHD 8      // C/HEADS

// Workspace layout (float offsets). Total ~134.3 MB.
#define OFF_QK   0
#define OFF_Y    0
#define OFF_V    16777216
#define OFF_GRAM 33554432
#define OFF_E    33556992

// ---------------------------------------------------------------------------
// K1: 1x1 conv x[B,64,N] -> qk[B,128,N]  (only q,k chunks of qkv; v chunk unused)
// launch_bounds(256,4): 128-VGPR cap so xv[64] stays in VGPRs (60-VGPR default
// spilled it to AGPRs via v_accvgpr shuttles -> 3x VALU inflation).
__global__ __launch_bounds__(256, 4) void k_qk1x1(const float* __restrict__ x,
    const float* __restrict__ w, const float* __restrict__ bias,
    float* __restrict__ qk) {
  const int bx = blockIdx.x;
  const int b = bx >> 8;                       // 256 blocks per batch
  const int n = ((bx & 255) << 8) + threadIdx.x;
  const float* xb = x + ((size_t)b * C) * NN + n;
  float xv[C];
#pragma unroll
  for (int c = 0; c < C; ++c) xv[c] = xb[(size_t)c * NN];
  float* qb = qk + ((size_t)b * 128) * NN + n;
#pragma unroll 2
  for (int o = 0; o < 128; ++o) {
    float acc = bias[o];
#pragma unroll
    for (int c = 0; c < C; ++c) acc = fmaf(w[o * C + c], xv[c], acc);
    qb[(size_t)o * NN] = acc;
  }
}

// ---------------------------------------------------------------------------
__global__ void k_zero_gram(float* __restrict__ g) {
  int i = blockIdx.x * 256 + threadIdx.x;
  if (i < B * HEADS * 80) g[i] = 0.f;
}

// ---------------------------------------------------------------------------
// K2: depthwise 3x3 (+bias) fused with Gram/norm accumulation.
// acc[80] needs the 256-VGPR budget -> launch_bounds(256,2).
#define DG_CHUNKS 32
#define DG_ITERS 8   // 32 chunks * 256 thr * 8 iters = 65536 positions
__global__ __launch_bounds__(256, 2) void k_dw_gram(const float* __restrict__ qk,
    const float* __restrict__ wdw, const float* __restrict__ bdw,
    float* __restrict__ gram) {
  const int bh = blockIdx.x / DG_CHUNKS;
  const int chunk = blockIdx.x % DG_CHUNKS;
  const int b = bh >> 3, h = bh & 7;
  const float* baseq = qk + ((size_t)b * 128 + h * CHD) * NN;
  const float* basek = qk + ((size_t)b * 128 + 64 + h * CHD) * NN;
  float acc[80];
#pragma unroll
  for (int i = 0; i < 80; ++i) acc[i] = 0.f;
  for (int it = 0; it < DG_ITERS; ++it) {
    const int n = chunk * (DG_ITERS * 256) + it * 256 + (int)threadIdx.x;
    const int py = n >> 8, px = n & 255;
    float qv[CHD], kv[CHD];
#pragma unroll
    for (int c = 0; c < CHD; ++c) {
      const int chq = h * CHD + c;
      const int chk = 64 + h * CHD + c;
      float aq = bdw[chq], ak = bdw[chk];
#pragma unroll
      for (int dy = -1; dy <= 1; ++dy) {
        const int yy = py + dy;
        if (yy < 0 || yy > IMG_H - 1) continue;
#pragma unroll
        for (int dx = -1; dx <= 1; ++dx) {
          const int xx = px + dx;
          if (xx < 0 || xx > IMG_W - 1) continue;
          const int nn2 = yy * IMG_W + xx;
          const int t = (dy + 1) * 3 + (dx + 1);
          aq = fmaf(wdw[chq * 9 + t], baseq[(size_t)c * NN + nn2], aq);
          ak = fmaf(wdw[chk * 9 + t], basek[(size_t)c * NN + nn2], ak);
        }
      }
      qv[c] = aq; kv[c] = ak;
    }
#pragma unroll
    for (int c = 0; c < CHD; ++c)
#pragma unroll
      for (int d = 0; d < CHD; ++d)
        acc[c * 8 + d] = fmaf(qv[c], kv[d], acc[c * 8 + d]);
#pragma unroll
    for (int c = 0; c < CHD; ++c) acc[64 + c] = fmaf(qv[c], qv[c], acc[64 + c]);
#pragma unroll
    for (int c = 0; c < CHD; ++c) acc[72 + c] = fmaf(kv[c], kv[c], acc[72 + c]);
  }
  const int lane = threadIdx.x & 63;
  float* gout = gram + bh * 80;
#pragma unroll 1
  for (int i = 0; i < 80; ++i) {
    float s = acc[i];
#pragma unroll
    for (int off = 32; off > 0; off >>= 1) s += __shfl_down(s, off, 64);
    if (lane == 0) atomicAdd(&gout[i], s);
  }
}

// ---------------------------------------------------------------------------
// K3: y = BN(conv1x1(x, w_m1))  (eval-mode BN folded to scale/shift)
__global__ __launch_bounds__(256, 4) void k_m1_bn(const float* __restrict__ x,
    const float* __restrict__ w, const float* __restrict__ gamma,
    const float* __restrict__ beta, const float* __restrict__ mean,
    const float* __restrict__ var, float* __restrict__ y) {
  const int bx = blockIdx.x;
  const int b = bx >> 8;
  const int n = ((bx & 255) << 8) + threadIdx.x;
  const float* xb = x + ((size_t)b * C) * NN + n;
  float xv[C];
#pragma unroll
  for (int c = 0; c < C; ++c) xv[c] = xb[(size_t)c * NN];
  float* yb = y + ((size_t)b * C) * NN + n;
#pragma unroll 2
  for (int o = 0; o < C; ++o) {
    float acc = 0.f;
#pragma unroll
    for (int c = 0; c < C; ++c) acc = fmaf(w[o * C + c], xv[c], acc);
    const float sc = gamma[o] * rsqrtf(var[o] + 1e-5f);
    yb[(size_t)o * NN] = (acc - mean[o]) * sc + beta[o];
  }
}

// ---------------------------------------------------------------------------
// K4: x2 = sigmoid(conv5x5(y)); v = x * (1 + x2). 16x16 output tile per block,
// 64 out-channel accumulators per thread. launch_bounds(256,2): 256-VGPR cap
// so acc[64]+inv[25] stay in VGPRs (default 60-VGPR budget shuttled acc via
// v_accvgpr -> VALUBusy 65% at only 21 TF).
#define ICB 4
__global__ __launch_bounds__(256, 2) void k_conv5_v(const float* __restrict__ y,
    const float* __restrict__ w2, const float* __restrict__ x,
    float* __restrict__ v) {
  const int bx = blockIdx.x;
  const int b = bx >> 8;
  const int tile = bx & 255;
  const int ty0 = (tile >> 4) * 16;
  const int tx0 = (tile & 15) * 16;
  const int tx = threadIdx.x & 15, ty = threadIdx.x >> 4;
  const float* yb = y + ((size_t)b * C) * NN;
  __shared__ float tile_s[ICB * 400];  // ICB channels of 20x20 halo tile
  float acc[C];
#pragma unroll
  for (int o = 0; o < C; ++o) acc[o] = 0.f;
  for (int c0 = 0; c0 < C; c0 += ICB) {
    __syncthreads();
    for (int i = threadIdx.x; i < ICB * 400; i += 256) {
      const int cc = i / 400, p = i % 400;
      const int r = p / 20, cl = p % 20;
      const int gy = ty0 - 2 + r, gx = tx0 - 2 + cl;
      float val = 0.f;
      if (gy >= 0 && gy < IMG_H && gx >= 0 && gx < IMG_W)
        val = yb[(size_t)(c0 + cc) * NN + gy * IMG_W + gx];
      tile_s[i] = val;
    }
    __syncthreads();
#pragma unroll 1
    for (int cc = 0; cc < ICB; ++cc) {
      float inv[25];
#pragma unroll
      for (int i = 0; i < 5; ++i)
#pragma unroll
        for (int j = 0; j < 5; ++j)
          inv[i * 5 + j] = tile_s[cc * 400 + (ty + i) * 20 + tx + j];
      const float* wc = w2 + (size_t)(c0 + cc) * 25;
#pragma unroll
      for (int o = 0; o < C; ++o) {
        const float* wo = wc + (size_t)o * (C * 25);
        float a = acc[o];
#pragma unroll
        for (int t = 0; t < 25; ++t) a = fmaf(wo[t], inv[t], a);
        acc[o] = a;
      }
    }
  }
  const int n = (ty0 + ty) * IMG_W + tx0 + tx;
  const float* xb = x + ((size_t)b * C) * NN + n;
  float* vb = v + ((size_t)b * C) * NN + n;
#pragma unroll
  for (int o = 0; o < C; ++o) {
    const float sg = 1.f / (1.f + __expf(-acc[o]));
    const float xval = xb[(size_t)o * NN];
    vb[(size_t)o * NN] = xval * (1.f + sg);
  }
}

// ---------------------------------------------------------------------------
// K6: softmax(attn) from gram+norms, then fold project_out weights:
// E[b][o][cv] = sum_{c'} wproj[o, h*8+c'] * attn[b,h,c',d]   (cv = h*8+d)
__global__ __launch_bounds__(256) void k_attn_e(const float* __restrict__ gram,
    const float* __restrict__ temp, const float* __restrict__ wproj,
    float* __restrict__ E) {
  __shared__ float attn[B * HEADS * CHD * CHD];  // 2048
  const int t = threadIdx.x;
  {
    const int b = t >> 6, h = (t >> 3) & 7, c = t & 7;
    const float* g = gram + (b * HEADS + h) * 80;
    const float qn = fmaxf(sqrtf(g[64 + c]), 1e-12f);
    const float tp = temp[h];
    float row[8];
    float mx = -1e30f;
#pragma unroll
    for (int d = 0; d < 8; ++d) {
      const float kn = fmaxf(sqrtf(g[72 + d]), 1e-12f);
      row[d] = g[c * 8 + d] / (qn * kn) * tp;
      mx = fmaxf(mx, row[d]);
    }
    float s = 0.f;
#pragma unroll
    for (int d = 0; d < 8; ++d) { row[d] = __expf(row[d] - mx); s += row[d]; }
    const float inv = 1.f / s;
#pragma unroll
    for (int d = 0; d < 8; ++d) attn[t * 8 + d] = row[d] * inv;
  }
  __syncthreads();
  for (int i = t; i < B * 64 * 64; i += 256) {
    const int b = i >> 12, o = (i >> 6) & 63, cv = i & 63;
    const int h = cv >> 3, d = cv & 7;
    float a = 0.f;
#pragma unroll
    for (int c2 = 0; c2 < 8; ++c2)
      a += wproj[o * C + h * 8 + c2] * attn[((b * HEADS + h) * 8 + c2) * 8 + d];
    E[i] = a;
  }
}

// ---------------------------------------------------------------------------
// K7: out[b,o,n] = bproj[o] + sum_cv E[b,o,cv] * v[b,cv,n]
__global__ __launch_bounds__(256, 4) void k_out(const float* __restrict__ v,
    const float* __restrict__ E, const float* __restrict__ bproj,
    float* __restrict__ out) {
  const int bx = blockIdx.x;
  const int b = bx >> 8;
  const int n = ((bx & 255) << 8) + threadIdx.x;
  const float* vb = v + ((size_t)b * C) * NN + n;
  float vv[C];
#pragma unroll
  for (int c = 0; c < C; ++c) vv[c] = vb[(size_t)c * NN];
  const float* Eb = E + b * 4096;
  float* ob = out + ((size_t)b * C) * NN + n;
#pragma unroll 2
  for (int o = 0; o < C; ++o) {
    float acc = bproj[o];
#pragma unroll
    for (int c = 0; c < C; ++c) acc = fmaf(Eb[o * C + c], vv[c], acc);
    ob[(size_t)o * NN] = acc;
  }
}

// ---------------------------------------------------------------------------
extern "C" void kernel_launch(void* const* d_in, const int* in_sizes, int n_in,
                              void* d_out, int out_size, void* d_ws, size_t ws_size,
                              hipStream_t stream) {
  const float* x     = (const float*)d_in[0];
  const float* wqkv  = (const float*)d_in[1];
  const float* bqkv  = (const float*)d_in[2];
  const float* wdw   = (const float*)d_in[3];
  const float* bdw   = (const float*)d_in[4];
  const float* wproj = (const float*)d_in[5];
  const float* bproj = (const float*)d_in[6];
  const float* temp  = (const float*)d_in[7];
  const float* wm1   = (const float*)d_in[8];
  const float* gamma = (const float*)d_in[9];
  const float* beta  = (const float*)d_in[10];
  const float* mean  = (const float*)d_in[11];
  const float* var   = (const float*)d_in[12];
  const float* wm2   = (const float*)d_in[13];

  float* ws   = (float*)d_ws;
  float* qk   = ws + OFF_QK;
  float* ybuf = ws + OFF_Y;
  float* vbuf = ws + OFF_V;
  float* gram = ws + OFF_GRAM;
  float* Ebuf = ws + OFF_E;
  float* out  = (float*)d_out;

  k_qk1x1<<<dim3(B * 256), dim3(256), 0, stream>>>(x, wqkv, bqkv, qk);
  k_zero_gram<<<dim3(10), dim3(256), 0, stream>>>(gram);
  k_dw_gram<<<dim3(B * HEADS * DG_CHUNKS), dim3(256), 0, stream>>>(qk, wdw, bdw, gram);
  // y/v reuse the qk region; stream order guarantees k_dw_gram finished first
  k_m1_bn<<<dim3(B * 256), dim3(256), 0, stream>>>(x, wm1, gamma, beta, mean, var, ybuf);
  k_conv5_v<<<dim3(B * 256), dim3(256), 0, stream>>>(ybuf, wm2, x, vbuf);
  k_attn_e<<<dim3(1), dim3(256), 0, stream>>>(gram, temp, wproj, Ebuf);
  k_out<<<dim3(B * 256), dim3(256), 0, stream>>>(vbuf, Ebuf, bproj, out);
}

// Round 4
// 747.962 us; speedup vs baseline: 4.9070x; 4.9070x over previous
//
#include <hip/hip_runtime.h>
#include <math.h>

#define B 4
#define C 64
#define NN 65536
#define IMG 256

typedef __attribute__((ext_vector_type(8))) short short8;
typedef __attribute__((ext_vector_type(4))) float f32x4;

__device__ inline float bf2f(short s) {
  union { unsigned u; float f; } v; v.u = ((unsigned)(unsigned short)s) << 16; return v.f;
}
__device__ inline short f2bf(float f) {
  union { float f; unsigned u; } v; v.f = f;
  unsigned r = v.u + 0x7FFFu + ((v.u >> 16) & 1u);  // RNE
  return (short)(r >> 16);
}

// ---------------------------------------------------------------------------
// K1: 1x1 conv x[b,64,N] fp32 -> qk[b,128,N] bf16 (q,k chunks only).
// acc[32]+xv[16] chunking keeps per-thread arrays small (no AGPR shuttles).
__global__ __launch_bounds__(256, 4) void k_qk1x1(const float* __restrict__ x,
    const float* __restrict__ w, const float* __restrict__ bias,
    short* __restrict__ qk) {
  const int b = blockIdx.x >> 8;
  const int n = ((blockIdx.x & 255) << 8) + threadIdx.x;
  const float* xb = x + ((size_t)b * C) * NN + n;
  short* qb = qk + ((size_t)b * 128) * NN + n;
  for (int oc = 0; oc < 4; ++oc) {
    float acc[32];
#pragma unroll
    for (int o = 0; o < 32; ++o) acc[o] = bias[oc * 32 + o];
    for (int cb = 0; cb < 4; ++cb) {
      float xv[16];
#pragma unroll
      for (int j = 0; j < 16; ++j) xv[j] = xb[(size_t)(cb * 16 + j) * NN];
#pragma unroll
      for (int o = 0; o < 32; ++o)
#pragma unroll
        for (int j = 0; j < 16; ++j)
          acc[o] = fmaf(w[(oc * 32 + o) * C + cb * 16 + j], xv[j], acc[o]);
    }
#pragma unroll
    for (int o = 0; o < 32; ++o) qb[(size_t)(oc * 32 + o) * NN] = f2bf(acc[o]);
  }
}

// ---------------------------------------------------------------------------
// K2: depthwise 3x3 (+bias) on qk, writing STACKED per-head layout
// qkdw[(b*8+h)*16 + r][N], r 0..7 = q rows, 8..15 = k rows (for MFMA gram).
__global__ __launch_bounds__(256) void k_dw(const short* __restrict__ qk,
    const float* __restrict__ wdw, const float* __restrict__ bdw,
    short* __restrict__ qkdw) {
  const int crow = blockIdx.x >> 8;  // b*128 + h*16 + r
  const int n = ((blockIdx.x & 255) << 8) + threadIdx.x;
  const int b = crow >> 7, cidx = crow & 127;
  const int h = cidx >> 4, r = cidx & 15;
  const int ch = (r < 8) ? (h * 8 + r) : (64 + h * 8 + (r - 8));
  const int py = n >> 8, px = n & 255;
  const short* src = qk + ((size_t)b * 128 + ch) * NN;
  float acc = bdw[ch];
#pragma unroll
  for (int dy = -1; dy <= 1; ++dy) {
    const int yy = py + dy; if (yy < 0 || yy > 255) continue;
#pragma unroll
    for (int dx = -1; dx <= 1; ++dx) {
      const int xx = px + dx; if (xx < 0 || xx > 255) continue;
      acc = fmaf(wdw[ch * 9 + (dy + 1) * 3 + (dx + 1)], bf2f(src[yy * 256 + xx]), acc);
    }
  }
  qkdw[(size_t)crow * NN + n] = f2bf(acc);
}

// ---------------------------------------------------------------------------
__global__ void k_zero(float* __restrict__ g, int nelem) {
  int i = blockIdx.x * 256 + threadIdx.x;
  if (i < nelem) g[i] = 0.f;
}

// ---------------------------------------------------------------------------
// K3: gram2[bh][16][16] = S·S^T via MFMA; S = qkdw[bh] (16 rows x N).
// A-frag == B-frag (same lane layout), so one 16B load feeds mfma(a,a,acc).
__global__ __launch_bounds__(256, 4) void k_gram(const short* __restrict__ qkdw,
    float* __restrict__ gram2) {
  const int bh = blockIdx.x >> 3, chunk = blockIdx.x & 7;
  const int wave = threadIdx.x >> 6, lane = threadIdx.x & 63;
  const int quad = lane >> 4, l15 = lane & 15;
  const short* S = qkdw + (size_t)bh * 16 * NN;
  const int n0 = chunk * 8192 + wave * 2048;
  f32x4 acc = {0.f, 0.f, 0.f, 0.f};
  for (int s = 0; s < 64; ++s) {
    const short8 a = *(const short8*)(S + (size_t)l15 * NN + n0 + s * 32 + quad * 8);
    acc = __builtin_amdgcn_mfma_f32_16x16x32_bf16(a, a, acc, 0, 0, 0);
  }
  float* g = gram2 + bh * 256;  // D[m][col]: m=quad*4+reg, col=l15
#pragma unroll
  for (int reg = 0; reg < 4; ++reg)
    atomicAdd(&g[(quad * 4 + reg) * 16 + l15], acc[reg]);
}

// ---------------------------------------------------------------------------
// K4: pack w2 (OIHW 64x64x5x5 fp32) into A-fragment order:
// apack[t][cc][mt][lane][j] = bf16 w2[o=mt*16+(lane&15)][c=cc*32+(lane>>4)*8+j][t]
__global__ __launch_bounds__(256) void k_pack_w2(const float* __restrict__ w2,
    short* __restrict__ apack) {
  for (int idx = threadIdx.x + blockIdx.x * 256; idx < 25 * 2 * 4 * 64 * 8; idx += 256 * 64) {
    const int j = idx & 7, lane = (idx >> 3) & 63, mt = (idx >> 9) & 3,
              cc = (idx >> 11) & 1, t = idx >> 12;
    const int o = mt * 16 + (lane & 15);
    const int c = cc * 32 + (lane >> 4) * 8 + j;
    apack[idx] = f2bf(w2[((size_t)o * 64 + c) * 25 + t]);
  }
}

// ---------------------------------------------------------------------------
// K5: y = BN(conv1x1(x)) -> y_t bf16 CHANNEL-INNERMOST [b][n][64] via LDS repack
// (so conv5 staging is 16B-coalesced on both global and LDS sides).
__global__ __launch_bounds__(256, 4) void k_m1_bn(const float* __restrict__ x,
    const float* __restrict__ w, const float* __restrict__ gamma,
    const float* __restrict__ beta, const float* __restrict__ mean,
    const float* __restrict__ var, short* __restrict__ y_t) {
  __shared__ short lds[256 * 72];  // [n_local][64 ch + pad]
  const int b = blockIdx.x >> 8;
  const int n0 = (blockIdx.x & 255) << 8;
  const float* xb = x + ((size_t)b * C) * NN + n0 + threadIdx.x;
  for (int oc = 0; oc < 2; ++oc) {
    float acc[32];
#pragma unroll
    for (int o = 0; o < 32; ++o) acc[o] = 0.f;
    for (int cb = 0; cb < 4; ++cb) {
      float xv[16];
#pragma unroll
      for (int j = 0; j < 16; ++j) xv[j] = xb[(size_t)(cb * 16 + j) * NN];
#pragma unroll
      for (int o = 0; o < 32; ++o)
#pragma unroll
        for (int j = 0; j < 16; ++j)
          acc[o] = fmaf(w[(oc * 32 + o) * C + cb * 16 + j], xv[j], acc[o]);
    }
#pragma unroll
    for (int o = 0; o < 32; ++o) {
      const int og = oc * 32 + o;
      const float sc = gamma[og] * rsqrtf(var[og] + 1e-5f);
      lds[threadIdx.x * 72 + og] = f2bf((acc[o] - mean[og]) * sc + beta[og]);
    }
  }
  __syncthreads();
  short* dst = y_t + ((size_t)b * NN + n0) * 64;
  for (int idx = threadIdx.x; idx < 2048; idx += 256) {
    const int nl = idx >> 3, cb = idx & 7;
    *(short8*)(dst + (size_t)nl * 64 + cb * 8) = *(const short8*)(lds + nl * 72 + cb * 8);
  }
}

// ---------------------------------------------------------------------------
// K6: conv5x5 as implicit-GEMM MFMA. WG = 4 rows x 64 cols; wave = 1 row.
// K = 2 chunks of 32 ch x 25 taps; B-frags from LDS (8 ch contiguous),
// A-frags (weights) streamed from L2-hot apack. Epilogue: v = x*(1+sigmoid).
__global__ __launch_bounds__(256, 2) void k_conv5(const short* __restrict__ y_t,
    const short* __restrict__ apack, const float* __restrict__ x,
    short* __restrict__ v) {
  __shared__ short ylds[8 * 68 * 40];  // [row8][col68][ch32 pad40] = 43.5 KB
  const int b = blockIdx.x >> 8;
  const int rg = (blockIdx.x >> 2) & 63, cg = blockIdx.x & 3;
  const int r0 = rg * 4, x0 = cg * 64;
  const int wave = threadIdx.x >> 6, lane = threadIdx.x & 63;
  const int quad = lane >> 4, l15 = lane & 15;
  f32x4 acc[4][4];
#pragma unroll
  for (int mt = 0; mt < 4; ++mt)
#pragma unroll
    for (int nt = 0; nt < 4; ++nt) acc[mt][nt] = (f32x4){0.f, 0.f, 0.f, 0.f};
  for (int cc = 0; cc < 2; ++cc) {
    if (cc) __syncthreads();
    for (int idx = threadIdx.x; idx < 8 * 68 * 4; idx += 256) {
      const int rr = idx / 272, rem = idx - rr * 272;
      const int col = rem >> 2, cb = rem & 3;
      const int gr = r0 - 2 + rr, gc = x0 - 2 + col;
      short8 val = {0, 0, 0, 0, 0, 0, 0, 0};
      if (gr >= 0 && gr < 256 && gc >= 0 && gc < 256)
        val = *(const short8*)(y_t + ((size_t)b * NN + gr * 256 + gc) * 64 + cc * 32 + cb * 8);
      *(short8*)(ylds + (rr * 68 + col) * 40 + cb * 8) = val;
    }
    __syncthreads();
    for (int t = 0; t < 25; ++t) {
      const int dy = t / 5 - 2, dx = t % 5 - 2;
      short8 a[4];
#pragma unroll
      for (int mt = 0; mt < 4; ++mt)
        a[mt] = *(const short8*)(apack + (((t * 2 + cc) * 4 + mt) * 64 + lane) * 8);
      const int rr = wave + 2 + dy;
#pragma unroll
      for (int nt = 0; nt < 4; ++nt) {
        const int colL = nt * 16 + l15 + 2 + dx;
        const short8 bf = *(const short8*)(ylds + (rr * 68 + colL) * 40 + quad * 8);
#pragma unroll
        for (int mt = 0; mt < 4; ++mt)
          acc[mt][nt] = __builtin_amdgcn_mfma_f32_16x16x32_bf16(a[mt], bf, acc[mt][nt], 0, 0, 0);
      }
    }
  }
  const int row = r0 + wave;
#pragma unroll
  for (int mt = 0; mt < 4; ++mt)
#pragma unroll
    for (int nt = 0; nt < 4; ++nt)
#pragma unroll
      for (int reg = 0; reg < 4; ++reg) {
        const int o = mt * 16 + quad * 4 + reg;     // C/D: row m = quad*4+reg
        const int n = row * 256 + x0 + nt * 16 + l15;  // col = lane&15
        const float xv = x[((size_t)b * C + o) * NN + n];
        const float sg = 1.f / (1.f + __expf(-acc[mt][nt][reg]));
        v[((size_t)b * C + o) * NN + n] = f2bf(xv * (1.f + sg));
      }
}

// ---------------------------------------------------------------------------
// K7: softmax from gram2 diag/off-diag blocks, fold wproj -> E[b][64][64].
__global__ __launch_bounds__(256) void k_attn_e(const float* __restrict__ gram2,
    const float* __restrict__ temp, const float* __restrict__ wproj,
    float* __restrict__ E) {
  __shared__ float attn[2048];
  const int t = threadIdx.x;
  {
    const int b = t >> 6, h = (t >> 3) & 7, c = t & 7;
    const float* g = gram2 + (b * 8 + h) * 256;
    const float qn = fmaxf(sqrtf(g[c * 16 + c]), 1e-12f);
    const float tp = temp[h];
    float row[8];
    float mx = -1e30f;
#pragma unroll
    for (int d = 0; d < 8; ++d) {
      const float kn = fmaxf(sqrtf(g[(8 + d) * 16 + (8 + d)]), 1e-12f);
      row[d] = g[c * 16 + 8 + d] / (qn * kn) * tp;
      mx = fmaxf(mx, row[d]);
    }
    float s = 0.f;
#pragma unroll
    for (int d = 0; d < 8; ++d) { row[d] = __expf(row[d] - mx); s += row[d]; }
    const float inv = 1.f / s;
#pragma unroll
    for (int d = 0; d < 8; ++d) attn[t * 8 + d] = row[d] * inv;
  }
  __syncthreads();
  for (int i = t; i < B * 64 * 64; i += 256) {
    const int b = i >> 12, o = (i >> 6) & 63, cv = i & 63;
    const int h = cv >> 3, d = cv & 7;
    float a = 0.f;
#pragma unroll
    for (int c2 = 0; c2 < 8; ++c2)
      a += wproj[o * C + h * 8 + c2] * attn[((b * 8 + h) * 8 + c2) * 8 + d];
    E[i] = a;
  }
}

// ---------------------------------------------------------------------------
// K8: out[b,o,n] = bproj[o] + sum_c E[b,o,c] * v[b,c,n]   (v bf16)
__global__ __launch_bounds__(256, 4) void k_out(const short* __restrict__ v,
    const float* __restrict__ E, const float* __restrict__ bproj,
    float* __restrict__ out) {
  const int b = blockIdx.x >> 8;
  const int n = ((blockIdx.x & 255) << 8) + threadIdx.x;
  const short* vb = v + ((size_t)b * C) * NN + n;
  const float* Eb = E + b * 4096;
  float* ob = out + ((size_t)b * C) * NN + n;
  for (int oc = 0; oc < 2; ++oc) {
    float acc[32];
#pragma unroll
    for (int o = 0; o < 32; ++o) acc[o] = bproj[oc * 32 + o];
    for (int cb = 0; cb < 4; ++cb) {
      float vv[16];
#pragma unroll
      for (int j = 0; j < 16; ++j) vv[j] = bf2f(vb[(size_t)(cb * 16 + j) * NN]);
#pragma unroll
      for (int o = 0; o < 32; ++o)
#pragma unroll
        for (int j = 0; j < 16; ++j)
          acc[o] = fmaf(Eb[(oc * 32 + o) * C + cb * 16 + j], vv[j], acc[o]);
    }
#pragma unroll
    for (int o = 0; o < 32; ++o) ob[(size_t)(oc * 32 + o) * NN] = acc[o];
  }
}

// ---------------------------------------------------------------------------
// Workspace (bytes):
//  [0, 67108864)        qk bf16            ... later reused: y_t [0,33554432), v [33554432,67108864)
//  [67108864,134217728) qkdw bf16          ... later reused: apack (written after k_gram)
//  [134217728, +32768)  gram2 fp32
//  [134250496, +65536)  E fp32
extern "C" void kernel_launch(void* const* d_in, const int* in_sizes, int n_in,
                              void* d_out, int out_size, void* d_ws, size_t ws_size,
                              hipStream_t stream) {
  const float* x     = (const float*)d_in[0];
  const float* wqkv  = (const float*)d_in[1];
  const float* bqkv  = (const float*)d_in[2];
  const float* wdw   = (const float*)d_in[3];
  const float* bdw   = (const float*)d_in[4];
  const float* wproj = (const float*)d_in[5];
  const float* bproj = (const float*)d_in[6];
  const float* temp  = (const float*)d_in[7];
  const float* wm1   = (const float*)d_in[8];
  const float* gamma = (const float*)d_in[9];
  const float* beta  = (const float*)d_in[10];
  const float* mean  = (const float*)d_in[11];
  const float* var   = (const float*)d_in[12];
  const float* wm2   = (const float*)d_in[13];

  short* qk    = (short*)d_ws;
  short* qkdw  = (short*)d_ws + 33554432;
  short* y_t   = (short*)d_ws;                  // reuse after k_dw consumed qk
  short* vbuf  = (short*)d_ws + 16777216;
  short* apack = (short*)d_ws + 33554432;       // reuse after k_gram consumed qkdw
  float* gram2 = (float*)d_ws + 33554432;
  float* Ebuf  = gram2 + 8192;
  float* out   = (float*)d_out;

  k_qk1x1<<<dim3(B * 256), dim3(256), 0, stream>>>(x, wqkv, bqkv, qk);
  k_dw<<<dim3(512 * 256), dim3(256), 0, stream>>>(qk, wdw, bdw, qkdw);
  k_zero<<<dim3(32), dim3(256), 0, stream>>>(gram2, 8192);
  k_gram<<<dim3(256), dim3(256), 0, stream>>>(qkdw, gram2);
  k_pack_w2<<<dim3(64), dim3(256), 0, stream>>>(wm2, apack);
  k_m1_bn<<<dim3(B * 256), dim3(256), 0, stream>>>(x, wm1, gamma, beta, mean, var, y_t);
  k_conv5<<<dim3(B * 256), dim3(256), 0, stream>>>(y_t, apack, x, vbuf);
  k_attn_e<<<dim3(1), dim3(256), 0, stream>>>(gram2, temp, wproj, Ebuf);
  k_out<<<dim3(B * 256), dim3(256), 0, stream>>>(vbuf, Ebuf, bproj, out);
}

// Round 5
// 656.340 us; speedup vs baseline: 5.5920x; 1.1396x over previous
//
#include <hip/hip_runtime.h>
#include <math.h>

#define B 4
#define C 64
#define NN 65536

typedef __attribute__((ext_vector_type(8))) short short8;
typedef __attribute__((ext_vector_type(4))) float f32x4;

__device__ inline float bf2f(short s) {
  union { unsigned u; float f; } v; v.u = ((unsigned)(unsigned short)s) << 16; return v.f;
}
__device__ inline short f2bf(float f) {
  union { float f; unsigned u; } v; v.f = f;
  unsigned r = v.u + 0x7FFFu + ((v.u >> 16) & 1u);  // RNE
  return (short)(r >> 16);
}

// ---------------------------------------------------------------------------
// P1: pack w_qkv (first 128 rows) and w_m1 into MFMA A-frag order; zero gram2.
// A-frag (16x16x32): lane l holds A[m=l&15][k=(l>>4)*8+j], j=0..7.
__global__ void k_prep1(const float* __restrict__ wqkv, const float* __restrict__ wm1,
    short* __restrict__ apk, short* __restrict__ apm, float* __restrict__ gram2) {
  for (int idx = blockIdx.x * 256 + threadIdx.x; idx < 20480; idx += 16384) {
    if (idx < 8192) {
      const int j = idx & 7, lane = (idx >> 3) & 63, mt = (idx >> 9) & 7, cc = idx >> 12;
      const int o = mt * 16 + (lane & 15), c = cc * 32 + (lane >> 4) * 8 + j;
      apk[idx] = f2bf(wqkv[o * 64 + c]);
    } else if (idx < 12288) {
      const int k = idx - 8192;
      const int j = k & 7, lane = (k >> 3) & 63, mt = (k >> 9) & 3, cc = k >> 11;
      const int o = mt * 16 + (lane & 15), c = cc * 32 + (lane >> 4) * 8 + j;
      apm[k] = f2bf(wm1[o * 64 + c]);
    } else {
      gram2[idx - 12288] = 0.f;
    }
  }
}

// P2: pack w2 (OIHW 64x64x5x5) -> A-frag order [t][cc][mt][lane][j].
// Launched AFTER k_gram (its buffer aliases the dead qk region).
__global__ void k_prep2(const float* __restrict__ w2, short* __restrict__ apw2) {
  for (int idx = blockIdx.x * 256 + threadIdx.x; idx < 25 * 2 * 4 * 64 * 8; idx += 16384) {
    const int j = idx & 7, lane = (idx >> 3) & 63, mt = (idx >> 9) & 3,
              cc = (idx >> 11) & 1, t = idx >> 12;
    const int o = mt * 16 + (lane & 15);
    const int c = cc * 32 + (lane >> 4) * 8 + j;
    apw2[idx] = f2bf(w2[((size_t)o * 64 + c) * 25 + t]);
  }
}

// ---------------------------------------------------------------------------
// XT: x[b,c,n] fp32 -> x_t[b,n,64] bf16 (channel-innermost) via LDS transpose.
__global__ __launch_bounds__(256) void k_xt(const float* __restrict__ x,
    short* __restrict__ x_t) {
  __shared__ short lds[256 * 72];
  const int b = blockIdx.x >> 8, n0 = (blockIdx.x & 255) << 8;
  const int t = threadIdx.x;
#pragma unroll 4
  for (int c = 0; c < 64; ++c)
    lds[t * 72 + c] = f2bf(x[((size_t)(b * 64 + c)) * NN + n0 + t]);
  __syncthreads();
  short* dst = x_t + ((size_t)(b * NN + n0)) * 64;
#pragma unroll
  for (int it = 0; it < 8; ++it) {
    const int idx = it * 256 + t;
    const int nl = idx >> 3, cb = idx & 7;
    *(short8*)(dst + (size_t)nl * 64 + cb * 8) = *(const short8*)(lds + nl * 72 + cb * 8);
  }
}

// ---------------------------------------------------------------------------
// K1: qk 1x1 conv as MFMA GEMM: qk[b,o<128,n] = wqkv.x + b. B-frag straight
// from x_t (one short8 global load per k-chunk; no LDS).
__global__ __launch_bounds__(256, 4) void k_qk1x1(const short* __restrict__ x_t,
    const short* __restrict__ apk, const float* __restrict__ bias,
    short* __restrict__ qk) {
  const int b = blockIdx.x >> 10, ntile = blockIdx.x & 1023;
  const int wave = threadIdx.x >> 6, lane = threadIdx.x & 63;
  const int quad = lane >> 4, l15 = lane & 15;
  const int n = ntile * 64 + wave * 16 + l15;
  f32x4 acc[8];
#pragma unroll
  for (int mt = 0; mt < 8; ++mt) acc[mt] = (f32x4){0.f, 0.f, 0.f, 0.f};
#pragma unroll
  for (int cc = 0; cc < 2; ++cc) {
    const short8 bf = *(const short8*)(x_t + ((size_t)(b * NN + n)) * 64 + cc * 32 + quad * 8);
#pragma unroll
    for (int mt = 0; mt < 8; ++mt) {
      const short8 af = *(const short8*)(apk + ((cc * 8 + mt) * 64 + lane) * 8);
      acc[mt] = __builtin_amdgcn_mfma_f32_16x16x32_bf16(af, bf, acc[mt], 0, 0, 0);
    }
  }
#pragma unroll
  for (int mt = 0; mt < 8; ++mt)
#pragma unroll
    for (int reg = 0; reg < 4; ++reg) {
      const int o = mt * 16 + quad * 4 + reg;
      qk[((size_t)(b * 128 + o)) * NN + n] = f2bf(acc[mt][reg] + bias[o]);
    }
}

// ---------------------------------------------------------------------------
// K2: FUSED depthwise-3x3 + Gram. Each lane computes 8 dw outputs of its row
// (row = lane&15: 0..7 q-rows, 8..15 k-rows of head h) straight from qk,
// then mfma(frag, frag) accumulates S.S^T (q.k dot products + both norms).
__global__ __launch_bounds__(256, 4) void k_gram(const short* __restrict__ qk,
    const float* __restrict__ wdw, const float* __restrict__ bdw,
    float* __restrict__ gram2) {
  const int bh = blockIdx.x >> 5, chunk = blockIdx.x & 31;
  const int b = bh >> 3, h = bh & 7;
  const int wave = threadIdx.x >> 6, lane = threadIdx.x & 63;
  const int quad = lane >> 4, l15 = lane & 15;
  const int ch = (l15 < 8) ? (h * 8 + l15) : (64 + h * 8 + (l15 - 8));
  const short* plane = qk + ((size_t)(b * 128 + ch)) * NN;
  float wreg[9];
#pragma unroll
  for (int i = 0; i < 9; ++i) wreg[i] = wdw[ch * 9 + i];
  const float bias = bdw[ch];
  const int n0 = chunk * 2048 + wave * 512;
  f32x4 acc = {0.f, 0.f, 0.f, 0.f};
  for (int s = 0; s < 16; ++s) {
    const int nb = n0 + s * 32 + quad * 8;
    const int py = nb >> 8, px0 = nb & 255;  // py is wave-uniform
    short8 frag;
#pragma unroll
    for (int j = 0; j < 8; ++j) {
      const int px = px0 + j;
      float a = bias;
#pragma unroll
      for (int dy = -1; dy <= 1; ++dy) {
        const int yy = py + dy;
        if (yy < 0 || yy > 255) continue;
#pragma unroll
        for (int dx = -1; dx <= 1; ++dx) {
          const int xx = px + dx;
          if (xx < 0 || xx > 255) continue;
          a = fmaf(wreg[(dy + 1) * 3 + (dx + 1)], bf2f(plane[yy * 256 + xx]), a);
        }
      }
      frag[j] = f2bf(a);
    }
    acc = __builtin_amdgcn_mfma_f32_16x16x32_bf16(frag, frag, acc, 0, 0, 0);
  }
  float* g = gram2 + bh * 256;
#pragma unroll
  for (int reg = 0; reg < 4; ++reg)
    atomicAdd(&g[(quad * 4 + reg) * 16 + l15], acc[reg]);
}

// ---------------------------------------------------------------------------
// K3: m1 1x1 conv + BN as MFMA GEMM -> y_t[b,n,64] bf16 via LDS repack.
__global__ __launch_bounds__(256, 4) void k_m1_bn(const short* __restrict__ x_t,
    const short* __restrict__ apm, const float* __restrict__ gamma,
    const float* __restrict__ beta, const float* __restrict__ mean,
    const float* __restrict__ var, short* __restrict__ y_t) {
  __shared__ short lds[64 * 72];
  const int b = blockIdx.x >> 10, ntile = blockIdx.x & 1023;
  const int wave = threadIdx.x >> 6, lane = threadIdx.x & 63;
  const int quad = lane >> 4, l15 = lane & 15;
  const int n = ntile * 64 + wave * 16 + l15;
  f32x4 acc[4];
#pragma unroll
  for (int mt = 0; mt < 4; ++mt) acc[mt] = (f32x4){0.f, 0.f, 0.f, 0.f};
#pragma unroll
  for (int cc = 0; cc < 2; ++cc) {
    const short8 bf = *(const short8*)(x_t + ((size_t)(b * NN + n)) * 64 + cc * 32 + quad * 8);
#pragma unroll
    for (int mt = 0; mt < 4; ++mt) {
      const short8 af = *(const short8*)(apm + ((cc * 4 + mt) * 64 + lane) * 8);
      acc[mt] = __builtin_amdgcn_mfma_f32_16x16x32_bf16(af, bf, acc[mt], 0, 0, 0);
    }
  }
#pragma unroll
  for (int mt = 0; mt < 4; ++mt)
#pragma unroll
    for (int reg = 0; reg < 4; ++reg) {
      const int o = mt * 16 + quad * 4 + reg;
      const float sc = gamma[o] * rsqrtf(var[o] + 1e-5f);
      lds[(wave * 16 + l15) * 72 + o] = f2bf((acc[mt][reg] - mean[o]) * sc + beta[o]);
    }
  __syncthreads();
  short* dst = y_t + ((size_t)(b * NN + ntile * 64)) * 64;
#pragma unroll
  for (int it = 0; it < 2; ++it) {
    const int idx = it * 256 + threadIdx.x;
    const int lcol = idx >> 3, cb = idx & 7;
    *(short8*)(dst + (size_t)lcol * 64 + cb * 8) = *(const short8*)(lds + lcol * 72 + cb * 8);
  }
}

// ---------------------------------------------------------------------------
// K4: conv5x5 implicit-GEMM MFMA; epilogue v = x*(1+sigmoid(.)) written
// channel-innermost v_t[b,n,64] via LDS repack (reuses the staging LDS).
__global__ __launch_bounds__(256, 2) void k_conv5(const short* __restrict__ y_t,
    const short* __restrict__ apw2, const short* __restrict__ x_t,
    short* __restrict__ v_t) {
  __shared__ short slds[8 * 68 * 40];  // staging: [row8][col68][ch32+pad] = 43.5KB
  const int b = blockIdx.x >> 8;
  const int rg = (blockIdx.x >> 2) & 63, cg = blockIdx.x & 3;
  const int r0 = rg * 4, x0 = cg * 64;
  const int wave = threadIdx.x >> 6, lane = threadIdx.x & 63;
  const int quad = lane >> 4, l15 = lane & 15;
  f32x4 acc[4][4];
#pragma unroll
  for (int mt = 0; mt < 4; ++mt)
#pragma unroll
    for (int nt = 0; nt < 4; ++nt) acc[mt][nt] = (f32x4){0.f, 0.f, 0.f, 0.f};
  for (int cc = 0; cc < 2; ++cc) {
    if (cc) __syncthreads();
    for (int idx = threadIdx.x; idx < 8 * 68 * 4; idx += 256) {
      const int rr = idx / 272, rem = idx - rr * 272;
      const int col = rem >> 2, cb = rem & 3;
      const int gr = r0 - 2 + rr, gc = x0 - 2 + col;
      short8 val = {0, 0, 0, 0, 0, 0, 0, 0};
      if (gr >= 0 && gr < 256 && gc >= 0 && gc < 256)
        val = *(const short8*)(y_t + ((size_t)(b * NN + gr * 256 + gc)) * 64 + cc * 32 + cb * 8);
      *(short8*)(slds + (rr * 68 + col) * 40 + cb * 8) = val;
    }
    __syncthreads();
    for (int t = 0; t < 25; ++t) {
      const int dy = t / 5 - 2, dx = t % 5 - 2;
      short8 a[4];
#pragma unroll
      for (int mt = 0; mt < 4; ++mt)
        a[mt] = *(const short8*)(apw2 + (((t * 2 + cc) * 4 + mt) * 64 + lane) * 8);
      const int rr = wave + 2 + dy;
#pragma unroll
      for (int nt = 0; nt < 4; ++nt) {
        const int colL = nt * 16 + l15 + 2 + dx;
        const short8 bf = *(const short8*)(slds + (rr * 68 + colL) * 40 + quad * 8);
#pragma unroll
        for (int mt = 0; mt < 4; ++mt)
          acc[mt][nt] = __builtin_amdgcn_mfma_f32_16x16x32_bf16(a[mt], bf, acc[mt][nt], 0, 0, 0);
      }
    }
  }
  __syncthreads();  // done reading staging; reuse slds as [row4][col64][72]
  const int row = r0 + wave;
#pragma unroll
  for (int mt = 0; mt < 4; ++mt)
#pragma unroll
    for (int nt = 0; nt < 4; ++nt)
#pragma unroll
      for (int reg = 0; reg < 4; ++reg) {
        const int o = mt * 16 + quad * 4 + reg;
        const int lcol = nt * 16 + l15;
        const float xv = bf2f(x_t[((size_t)(b * NN + row * 256 + x0 + lcol)) * 64 + o]);
        const float sg = 1.f / (1.f + __expf(-acc[mt][nt][reg]));
        slds[(wave * 64 + lcol) * 72 + o] = f2bf(xv * (1.f + sg));
      }
  __syncthreads();
#pragma unroll
  for (int it = 0; it < 8; ++it) {
    const int idx = it * 256 + threadIdx.x;
    const int cb = idx & 7, lcol = (idx >> 3) & 63, rr = idx >> 9;
    *(short8*)(v_t + ((size_t)(b * NN + (r0 + rr) * 256 + x0 + lcol)) * 64 + cb * 8) =
        *(const short8*)(slds + (rr * 64 + lcol) * 72 + cb * 8);
  }
}

// ---------------------------------------------------------------------------
// K5: softmax from gram2, fold wproj, emit E directly in bf16 A-frag order:
// Epack[b][cc][mt][lane][j] with A[m=o][k=cv].
__global__ __launch_bounds__(256) void k_attn_e(const float* __restrict__ gram2,
    const float* __restrict__ temp, const float* __restrict__ wproj,
    short* __restrict__ Epack) {
  __shared__ float attn[2048];
  const int t = threadIdx.x;
  {
    const int b = t >> 6, h = (t >> 3) & 7, c = t & 7;
    const float* g = gram2 + (b * 8 + h) * 256;
    const float qn = fmaxf(sqrtf(g[c * 16 + c]), 1e-12f);
    const float tp = temp[h];
    float row[8];
    float mx = -1e30f;
#pragma unroll
    for (int d = 0; d < 8; ++d) {
      const float kn = fmaxf(sqrtf(g[(8 + d) * 16 + (8 + d)]), 1e-12f);
      row[d] = g[c * 16 + 8 + d] / (qn * kn) * tp;
      mx = fmaxf(mx, row[d]);
    }
    float s = 0.f;
#pragma unroll
    for (int d = 0; d < 8; ++d) { row[d] = __expf(row[d] - mx); s += row[d]; }
    const float inv = 1.f / s;
#pragma unroll
    for (int d = 0; d < 8; ++d) attn[t * 8 + d] = row[d] * inv;
  }
  __syncthreads();
  for (int idx = t; idx < 16384; idx += 256) {
    const int j = idx & 7, lane = (idx >> 3) & 63, mt = (idx >> 9) & 3,
              cc = (idx >> 11) & 1, b = idx >> 12;
    const int o = mt * 16 + (lane & 15);
    const int cv = cc * 32 + (lane >> 4) * 8 + j;
    const int h = cv >> 3, d = cv & 7;
    float a = 0.f;
#pragma unroll
    for (int c2 = 0; c2 < 8; ++c2)
      a += wproj[o * 64 + h * 8 + c2] * attn[((b * 8 + h) * 8 + c2) * 8 + d];
    Epack[idx] = f2bf(a);
  }
}

// ---------------------------------------------------------------------------
// K6: out[b,o,n] = bproj[o] + E[b].v_t  as per-batch MFMA GEMM, fp32 stores.
__global__ __launch_bounds__(256, 4) void k_out(const short* __restrict__ v_t,
    const short* __restrict__ Epack, const float* __restrict__ bproj,
    float* __restrict__ out) {
  const int b = blockIdx.x >> 10, ntile = blockIdx.x & 1023;
  const int wave = threadIdx.x >> 6, lane = threadIdx.x & 63;
  const int quad = lane >> 4, l15 = lane & 15;
  const int n = ntile * 64 + wave * 16 + l15;
  f32x4 acc[4];
#pragma unroll
  for (int mt = 0; mt < 4; ++mt) acc[mt] = (f32x4){0.f, 0.f, 0.f, 0.f};
#pragma unroll
  for (int cc = 0; cc < 2; ++cc) {
    const short8 bf = *(const short8*)(v_t + ((size_t)(b * NN + n)) * 64 + cc * 32 + quad * 8);
#pragma unroll
    for (int mt = 0; mt < 4; ++mt) {
      const short8 af = *(const short8*)(Epack + (((b * 2 + cc) * 4 + mt) * 64 + lane) * 8);
      acc[mt] = __builtin_amdgcn_mfma_f32_16x16x32_bf16(af, bf, acc[mt], 0, 0, 0);
    }
  }
#pragma unroll
  for (int mt = 0; mt < 4; ++mt)
#pragma unroll
    for (int reg = 0; reg < 4; ++reg) {
      const int o = mt * 16 + quad * 4 + reg;
      out[((size_t)(b * 64 + o)) * NN + n] = acc[mt][reg] + bproj[o];
    }
}

// ---------------------------------------------------------------------------
// Workspace (byte offsets), total 134307840 <= proven ws capacity:
//  [0,   64M)  qk bf16 [b][128][N]  -> after k_gram: v_t [0,32M), apw2 @32M
//  [64M, 96M)  x_t bf16 [b][n][64]
//  [96M,128M)  y_t bf16 [b][n][64]
//  [128M, ..)  gram2 32KB | apk 16KB | apm 8KB | Epack 32KB
extern "C" void kernel_launch(void* const* d_in, const int* in_sizes, int n_in,
                              void* d_out, int out_size, void* d_ws, size_t ws_size,
                              hipStream_t stream) {
  const float* x     = (const float*)d_in[0];
  const float* wqkv  = (const float*)d_in[1];
  const float* bqkv  = (const float*)d_in[2];
  const float* wdw   = (const float*)d_in[3];
  const float* bdw   = (const float*)d_in[4];
  const float* wproj = (const float*)d_in[5];
  const float* bproj = (const float*)d_in[6];
  const float* temp  = (const float*)d_in[7];
  const float* wm1   = (const float*)d_in[8];
  const float* gamma = (const float*)d_in[9];
  const float* beta  = (const float*)d_in[10];
  const float* mean  = (const float*)d_in[11];
  const float* var   = (const float*)d_in[12];
  const float* wm2   = (const float*)d_in[13];

  char* wsb = (char*)d_ws;
  short* qk    = (short*)(wsb);
  short* v_t   = (short*)(wsb);                       // aliases qk (after k_gram)
  short* apw2  = (short*)(wsb + 33554432);            // aliases qk tail (after k_gram)
  short* x_t   = (short*)(wsb + 67108864);
  short* y_t   = (short*)(wsb + 100663296);
  float* gram2 = (float*)(wsb + 134217728);
  short* apk   = (short*)(wsb + 134217728 + 32768);
  short* apm   = (short*)(wsb + 134217728 + 49152);
  short* Epack = (short*)(wsb + 134217728 + 57344);
  float* out   = (float*)d_out;

  k_prep1<<<dim3(64), dim3(256), 0, stream>>>(wqkv, wm1, apk, apm, gram2);
  k_xt<<<dim3(1024), dim3(256), 0, stream>>>(x, x_t);
  k_qk1x1<<<dim3(4096), dim3(256), 0, stream>>>(x_t, apk, bqkv, qk);
  k_gram<<<dim3(1024), dim3(256), 0, stream>>>(qk, wdw, bdw, gram2);
  k_prep2<<<dim3(64), dim3(256), 0, stream>>>(wm2, apw2);
  k_m1_bn<<<dim3(4096), dim3(256), 0, stream>>>(x_t, apm, gamma, beta, mean, var, y_t);
  k_conv5<<<dim3(1024), dim3(256), 0, stream>>>(y_t, apw2, x_t, v_t);
  k_attn_e<<<dim3(1), dim3(256), 0, stream>>>(gram2, temp, wproj, Epack);
  k_out<<<dim3(4096), dim3(256), 0, stream>>>(v_t, Epack, bproj, out);
}